// Round 5
// baseline (279.581 us; speedup 1.0000x reference)
//
#include <hip/hip_runtime.h>
#include <hip/hip_bf16.h>

// out[s,b,o] = sum_h in[s,b,h] * w[o,h]
// A = [M=8192, K=1024] fp32, W = [N=4096, K=1024] fp32 (B^T layout), C = [M,N] fp32.
//
// Round 6 -> 7: persistent 2-tile blocks. REVERTS round 6's LDS-bounce epilogue and
// XCD remap (net regression: not HBM-bound, bounce added 1M conflict cycles).
// Keeps round-2's verified double-barrier 8-phase body + precomputed ds_read offsets.
//
// Why: at K=1024 the 8-phase schedule is at its measured ceiling (~848 TF, m248);
// the remaining loss is round-boundary serialization: 512 blocks / 128KiB LDS =
// 2 strict dispatch rounds; occupancy 18% vs 25% ideal. New grid = 256 (1 block/CU,
// zero rounds); each block does two adjacent-N tiles (same bm -> tile2's A panels
// L2-hot). Tile 2's PROLOGUE IS FREE: it=7's previously-garbage stage slots
// (ph3..ph8 -> buf0.u1,u4,u3,u2 + buf1.u1,u4) are exactly the prologue pattern,
// now pointed at tile2 k=0/BK. Hazard ledger unchanged (same regions, same barrier
// distances as the verified clamped version).
//
// Stage-unit ledger (per iteration; E=buf0 tile, O=buf1 tile):
//   ph1 E.q(0,0) reads A0,B0  stages O.u2@kO     ph2 E.q(0,1) reads B1  stages O.u3@kO
//   ph3 E.q(1,1) reads A1     stages buf0.u1@sk2 ph4 E.q(1,0)           stages buf0.u4@sk2  GATE vmcnt(4)
//   ph5 O.q(0,0) reads A0,B0  stages buf0.u3@sk2 ph6 O.q(0,1) reads B1  stages buf0.u2@sk2
//   ph7 O.q(1,1) reads A1     stages buf1.u1@sk3 ph8 O.q(1,0)           stages buf1.u4@sk3  GATE vmcnt(4)
//   it<7 : sk2=kE+128, sk3=kE+192 (next/next-next K-tiles of current output tile)
//   it==7, tile0: sk2=0, sk3=BK with bn_next  (tile-2 prologue)
//   it==7, tile1: sk2=sk3=K-BK, bn (dead garbage, in-bounds; original behavior)
// Inter-tile: vmcnt(0) (stages landed) -> issue C stores (un-waited; tile2 ph4's
// vmcnt(4) over-waits them overlapped with 4 MFMA phases) -> barrier -> tile2 loop.

typedef __bf16 bf16x8_t __attribute__((ext_vector_type(8)));
typedef float f32x4_t __attribute__((ext_vector_type(4)));

constexpr int M = 8192;
constexpr int N = 4096;
constexpr int K = 1024;
constexpr int BM = 256;
constexpr int BN = 256;
constexpr int BK = 64;

// ---------------- fp32 -> bf16 convert, both tensors in one launch ----------
__global__ __launch_bounds__(256) void cvt_f32_bf16(const float* __restrict__ a,
                                                    const float* __restrict__ w,
                                                    __bf16* __restrict__ a_bf,
                                                    __bf16* __restrict__ w_bf) {
    size_t i = ((size_t)blockIdx.x * 256 + threadIdx.x) * 8;
    const float* src;
    __bf16* dst;
    if (i < (size_t)M * K) {
        src = a + i;
        dst = a_bf + i;
    } else {
        size_t j = i - (size_t)M * K;
        src = w + j;
        dst = w_bf + j;
    }
    float4 v0 = *(const float4*)(src);
    float4 v1 = *(const float4*)(src + 4);
    bf16x8_t o;
    o[0] = (__bf16)v0.x; o[1] = (__bf16)v0.y; o[2] = (__bf16)v0.z; o[3] = (__bf16)v0.w;
    o[4] = (__bf16)v1.x; o[5] = (__bf16)v1.y; o[6] = (__bf16)v1.z; o[7] = (__bf16)v1.w;
    *(bf16x8_t*)dst = o;
}

// ---------------- bf16 GEMM, 256x256 tile, persistent 2-tile blocks ----------
__global__ __launch_bounds__(512, 1) void gemm_bt(const __bf16* __restrict__ A,
                                                  const __bf16* __restrict__ B,
                                                  float* __restrict__ C) {
    // [buf][0=A,1=B][row][col]; row stride 64 bf16 = 128 B = 8 chunks of 16 B.
    // LDS slot (row, chunk c) holds global chunk c ^ (row & 7)  (both-sides involution).
    __shared__ __bf16 lds[2][2][256][BK];   // 128 KiB

    const int tid = threadIdx.x;
    const int lane = tid & 63;
    const int quad = lane >> 4;
    const int l16 = lane & 15;
    const int sa = l16 & 7;            // read-side swizzle key (= frag row & 7)
    const int wave = tid >> 6;         // 8 waves, 2(M) x 4(N)
    const int wm = wave >> 2;
    const int wn = wave & 3;

    // Persistent mapping: 256 blocks; block = (tm, tn-pair). Both tiles share bm.
    const int bid = blockIdx.x;        // 0..255
    const int bm = (bid >> 3) * BM;    // 32 tm values
    int bn = (bid & 7) * (2 * BN);     // tile 0 of the pair

    // staging per-thread geometry
    const int c8 = tid & 7;            // 16B chunk within a row
    const int r8 = (tid >> 3) & 7;     // dst row & 7 for every stage pattern
    const int scol = (c8 ^ r8) << 3;   // pre-swizzled global source column (elems)
    const int arow = tid >> 3;         // 0..63
    const int bq64 = ((tid >> 8) << 6);// 0 or 64
    const int brow = (tid >> 3) & 31;  // 0..31

    // Precomputed per-lane fragment byte offsets (within one buf).
    char* const ldsB0 = (char*)&lds[0][0][0][0];
    char* const ldsB1 = ldsB0 + 65536;
    const int aO0 = (wm * 128 + l16) * 128 + (((0 + quad) ^ sa) << 4);          // ks=0
    const int aO1 = (wm * 128 + l16) * 128 + (((4 + quad) ^ sa) << 4);          // ks=1
    const int bO0 = 32768 + (wn * 64 + l16) * 128 + (((0 + quad) ^ sa) << 4);   // ks=0
    const int bO1 = 32768 + (wn * 64 + l16) * 128 + (((4 + quad) ^ sa) << 4);   // ks=1

    f32x4_t acc[8][4] = {};

#define STAGE_A(buf, mh, k0)                                                        \
  do {                                                                              \
    _Pragma("unroll") for (int r_ = 0; r_ < 2; ++r_) {                              \
      int row_ = r_ * 128 + (mh) * 64 + arow;                                       \
      __builtin_amdgcn_global_load_lds(                                             \
          (const __attribute__((address_space(1))) unsigned int*)(                  \
              A + (size_t)(bm + row_) * K + (k0) + scol),                           \
          (__attribute__((address_space(3))) unsigned int*)(&lds[buf][0][row_][c8 * 8]), \
          16, 0, 0);                                                                \
    }                                                                               \
  } while (0)

#define STAGE_B(buf, nh, bnS, k0)                                                   \
  do {                                                                              \
    _Pragma("unroll") for (int r_ = 0; r_ < 2; ++r_) {                              \
      int row_ = r_ * 128 + bq64 + (nh) * 32 + brow;                                \
      __builtin_amdgcn_global_load_lds(                                             \
          (const __attribute__((address_space(1))) unsigned int*)(                  \
              B + (size_t)((bnS) + row_) * K + (k0) + scol),                        \
          (__attribute__((address_space(3))) unsigned int*)(&lds[buf][1][row_][c8 * 8]), \
          16, 0, 0);                                                                \
    }                                                                               \
  } while (0)

// ldsP: ldsB0 or ldsB1 (compile-time per phase)
#define LOAD_A(ldsP, mh)                                                            \
  do {                                                                              \
    _Pragma("unroll") for (int i_ = 0; i_ < 4; ++i_) {                              \
      a[i_][0] = *(const bf16x8_t*)((ldsP) + (mh) * 8192 + i_ * 2048 + aO0);        \
      a[i_][1] = *(const bf16x8_t*)((ldsP) + (mh) * 8192 + i_ * 2048 + aO1);        \
    }                                                                               \
  } while (0)

#define LOAD_B(ldsP, nh, bv)                                                        \
  do {                                                                              \
    _Pragma("unroll") for (int j_ = 0; j_ < 2; ++j_) {                              \
      bv[j_][0] = *(const bf16x8_t*)((ldsP) + (nh) * 4096 + j_ * 2048 + bO0);       \
      bv[j_][1] = *(const bf16x8_t*)((ldsP) + (nh) * 4096 + j_ * 2048 + bO1);       \
    }                                                                               \
  } while (0)

#define MFMA_Q(mh, nh, bv)                                                          \
  do {                                                                              \
    __builtin_amdgcn_s_setprio(1);                                                  \
    _Pragma("unroll") for (int i_ = 0; i_ < 4; ++i_)                                \
      _Pragma("unroll") for (int j_ = 0; j_ < 2; ++j_) {                            \
        acc[(mh) * 4 + i_][(nh) * 2 + j_] = __builtin_amdgcn_mfma_f32_16x16x32_bf16( \
            a[i_][0], bv[j_][0], acc[(mh) * 4 + i_][(nh) * 2 + j_], 0, 0, 0);       \
        acc[(mh) * 4 + i_][(nh) * 2 + j_] = __builtin_amdgcn_mfma_f32_16x16x32_bf16( \
            a[i_][1], bv[j_][1], acc[(mh) * 4 + i_][(nh) * 2 + j_], 0, 0, 0);       \
      }                                                                             \
    __builtin_amdgcn_s_setprio(0);                                                  \
  } while (0)

#define FENCE() asm volatile("" ::: "memory")
#define BAR()   do { FENCE(); __builtin_amdgcn_s_barrier(); FENCE(); } while (0)
#define LGKM0() asm volatile("s_waitcnt lgkmcnt(0)" ::: "memory")
#define LGKM8() asm volatile("s_waitcnt lgkmcnt(8)" ::: "memory")
#define VMCNT(n_) asm volatile("s_waitcnt vmcnt(" #n_ ")" ::: "memory")

    // Prologue (tile 0 of the pair): tile0 fully + tile1.{u1,u4}.
    // vmcnt(4) = first 8 of 12 loads landed = all of K-tile-0.
    STAGE_A(0, 0, 0);          // t0.u1
    STAGE_B(0, 0, bn, 0);      // t0.u2
    STAGE_B(0, 1, bn, 0);      // t0.u4
    STAGE_A(0, 1, 0);          // t0.u3
    STAGE_A(1, 0, BK);         // t1.u1
    STAGE_B(1, 1, bn, BK);     // t1.u4
    VMCNT(4);
    BAR();

    bf16x8_t a[4][2], b0[2][2], b1[2][2];

    for (int t = 0; t < 2; ++t) {
        const int bn_next = bn + BN;

        for (int it = 0; it < 8; ++it) {
            const int kO = it * 128 + 64;
            const bool last = (it == 7);
            // it<7: prefetch current tile's K-tiles; it==7: tile-2 prologue (t=0)
            // or dead in-bounds garbage (t=1).
            const int sbn = (last && t == 0) ? bn_next : bn;
            const int sk2 = last ? (t == 0 ? 0 : K - BK) : it * 128 + 128;
            const int sk3 = last ? (t == 0 ? BK : K - BK) : it * 128 + 192;

            // ph1: E q(0,0)
            LOAD_A(ldsB0, 0); LOAD_B(ldsB0, 0, b0);
            STAGE_B(1, 0, sbn == bn ? bn : bn, kO);   // O.u2 always current tile
            LGKM8();
            BAR(); LGKM0();
            MFMA_Q(0, 0, b0);
            BAR();

            // ph2: E q(0,1)
            LOAD_B(ldsB0, 1, b1);
            STAGE_A(1, 1, kO);                        // O.u3 always current tile
            BAR(); LGKM0();
            MFMA_Q(0, 1, b1);
            BAR();

            // ph3: E q(1,1)
            LOAD_A(ldsB0, 1);
            STAGE_A(0, 0, sk2);                       // buf0.u1
            BAR(); LGKM0();
            MFMA_Q(1, 1, b1);
            BAR();

            // ph4: E q(1,0); gate for tile O
            STAGE_B(0, 1, sbn, sk2);                  // buf0.u4
            BAR();
            MFMA_Q(1, 0, b0);
            VMCNT(4);
            BAR();

            // ph5: O q(0,0)
            LOAD_A(ldsB1, 0); LOAD_B(ldsB1, 0, b0);
            STAGE_A(0, 1, sk2);                       // buf0.u3
            LGKM8();
            BAR(); LGKM0();
            MFMA_Q(0, 0, b0);
            BAR();

            // ph6: O q(0,1)
            LOAD_B(ldsB1, 1, b1);
            STAGE_B(0, 0, sbn, sk2);                  // buf0.u2
            BAR(); LGKM0();
            MFMA_Q(0, 1, b1);
            BAR();

            // ph7: O q(1,1)
            LOAD_A(ldsB1, 1);
            STAGE_A(1, 0, sk3);                       // buf1.u1
            BAR(); LGKM0();
            MFMA_Q(1, 1, b1);
            BAR();

            // ph8: O q(1,0); gate
            STAGE_B(1, 1, sbn, sk3);                  // buf1.u4
            BAR();
            MFMA_Q(1, 0, b0);
            VMCNT(4);
            BAR();
        }

        // ---------------- per-tile epilogue -------------------------------
        // Drain this wave's outstanding stage loads (tile-2 prologue data) BEFORE
        // issuing stores, so the stores' acks don't sit in front of the drain.
        VMCNT(0);

        // Direct C stores from acc (un-waited; tile-2's first vmcnt(4) gate
        // over-waits their acks overlapped with 4 MFMA phases).
        {
            const int crow0 = bm + wm * 128 + quad * 4;
            const int ccol0 = bn + wn * 64 + l16;
#pragma unroll
            for (int i_ = 0; i_ < 8; ++i_)
#pragma unroll
                for (int j_ = 0; j_ < 4; ++j_)
#pragma unroll
                    for (int r_ = 0; r_ < 4; ++r_)
                        C[(size_t)(crow0 + i_ * 16 + r_) * N + (ccol0 + j_ * 16)] =
                            acc[i_][j_][r_];
        }

        if (t == 0) {
            // All waves' tile-2 stages are landed (each passed its own vmcnt(0)).
            BAR();
#pragma unroll
            for (int i_ = 0; i_ < 8; ++i_)
#pragma unroll
                for (int j_ = 0; j_ < 4; ++j_)
                    acc[i_][j_] = (f32x4_t){0.f, 0.f, 0.f, 0.f};
            bn = bn_next;
        }
    }

#undef STAGE_A
#undef STAGE_B
#undef LOAD_A
#undef LOAD_B
#undef MFMA_Q
#undef FENCE
#undef BAR
#undef LGKM0
#undef LGKM8
#undef VMCNT
}

extern "C" void kernel_launch(void* const* d_in, const int* in_sizes, int n_in,
                              void* d_out, int out_size, void* d_ws, size_t ws_size,
                              hipStream_t stream) {
    const float* in_f32 = (const float*)d_in[0];   // [M,K]
    const float* w_f32  = (const float*)d_in[1];   // [N,K]
    float* out = (float*)d_out;                     // [M,N]

    __bf16* A_bf = (__bf16*)d_ws;
    __bf16* W_bf = A_bf + (size_t)M * K;

    cvt_f32_bf16<<<((size_t)(M + N) * K) / (8 * 256), 256, 0, stream>>>(in_f32, w_f32, A_bf, W_bf);

    // 256 persistent blocks = 1/CU; each does 2 adjacent-N tiles.
    gemm_bt<<<256, 512, 0, stream>>>(A_bf, W_bf, out);
}

// Round 6
// 227.638 us; speedup vs baseline: 1.2282x; 1.2282x over previous
//
#include <hip/hip_runtime.h>
#include <hip/hip_bf16.h>

// out[s,b,o] = sum_h in[s,b,h] * w[o,h]
// A = [M=8192, K=1024] fp32, W = [N=4096, K=1024] fp32 (B^T layout), C = [M,N] fp32.
//
// Round 7: pipelined-read 8-phase. REVERTS round-6 LDS-bounce/XCD-remap and
// round-5 persistent blocks (both regressed). Baseline = round-2 body (81.5us),
// restructured so MFMA consumes fragments read in the PREVIOUS phase:
//   phase p: { stage 1 unit | MFMA_p (operands from p-1) | ds_reads for p+1 | [gate] | BAR }
// This removes the same-phase read->MFMA dependency that serialized LDS drain
// and MFMA windows (MfmaUtil 33%). Single fragment slots (a, b0, b1) survive:
// MFMA order q00,q01,q11,q10 makes every read target regs whose last use is the
// MFMA cluster issued earlier in the same phase (WAR; ds_read writeback lands
// after MFMA operand capture; compiler enforces). Barriers: 8/iter (was 16).
//
// Steady iteration (buf0 = K-tile 2it "E", buf1 = 2it+1 "O"); stage 1 unit/phase:
//   p1: stage buf1.B0'@k1 | MFMA q00(A0,B0)   | read B1        |          BAR
//   p2: stage buf0.A0@k2  | MFMA q01(A0,B1)   | read A1  (WAR) |          BAR
//   p3: stage buf0.B0@k2  | MFMA q11(A1,B1)   | --             | vmcnt(4) BAR   gate: buf1 landed
//   p4: stage buf0.B1@k2  | MFMA q10(A1,B0)   | read A0',B0'(WAR)|        BAR
//   p5: stage buf0.A1@k2  | MFMA q00'(A0',B0')| read B1'       |          BAR
//   p6: stage buf1.A0@k3  | MFMA q01'(A0',B1')| read A1' (WAR) |          BAR
//   p7: stage buf1.B1@k3  | MFMA q11'(A1',B1')| --             | vmcnt(4) BAR   gate: buf0-next landed
//   p8: stage buf1.A1@k3  | MFMA q10'(A1',B0')| read A0,B0 (WAR)|         BAR
// k1 = it*128+64 (real thru it=7), k2 = it*128+128, k3 = it*128+192 (clamped to
// K-BK at tail -> garbage into dead regions, in-bounds).
// Ledger checks (all verified): every stage >= its region's ds_read phase + 2;
// gate@p3 leaves p2,p3 stages (4 loads) in flight -> all buf1 units landed;
// gate@p7 leaves p6,p7 (4) in flight -> all buf0-next units (p2..p5) landed;
// reads of a freshly gated buffer only occur after the gate's barrier (p4, p8).
// Prologue: stage buf0{u1,u2,u4,u3}@0 + buf1{u1,u4,u3}@64 (14 loads), vmcnt(6)
// (= buf0 landed), BAR, read A0,B0 -> enter p1.

typedef __bf16 bf16x8_t __attribute__((ext_vector_type(8)));
typedef float f32x4_t __attribute__((ext_vector_type(4)));

constexpr int M = 8192;
constexpr int N = 4096;
constexpr int K = 1024;
constexpr int BM = 256;
constexpr int BN = 256;
constexpr int BK = 64;

// ---------------- fp32 -> bf16 convert, both tensors in one launch ----------
__global__ __launch_bounds__(256) void cvt_f32_bf16(const float* __restrict__ a,
                                                    const float* __restrict__ w,
                                                    __bf16* __restrict__ a_bf,
                                                    __bf16* __restrict__ w_bf) {
    size_t i = ((size_t)blockIdx.x * 256 + threadIdx.x) * 8;
    const float* src;
    __bf16* dst;
    if (i < (size_t)M * K) {
        src = a + i;
        dst = a_bf + i;
    } else {
        size_t j = i - (size_t)M * K;
        src = w + j;
        dst = w_bf + j;
    }
    float4 v0 = *(const float4*)(src);
    float4 v1 = *(const float4*)(src + 4);
    bf16x8_t o;
    o[0] = (__bf16)v0.x; o[1] = (__bf16)v0.y; o[2] = (__bf16)v0.z; o[3] = (__bf16)v0.w;
    o[4] = (__bf16)v1.x; o[5] = (__bf16)v1.y; o[6] = (__bf16)v1.z; o[7] = (__bf16)v1.w;
    *(bf16x8_t*)dst = o;
}

// ---------------- bf16 GEMM, 256x256 tile, pipelined-read 8-phase ------------
__global__ __launch_bounds__(512, 1) void gemm_bt(const __bf16* __restrict__ A,
                                                  const __bf16* __restrict__ B,
                                                  float* __restrict__ C) {
    // [buf][0=A,1=B][row][col]; row stride 64 bf16 = 128 B = 8 chunks of 16 B.
    // LDS slot (row, chunk c) holds global chunk c ^ (row & 7)  (both-sides involution).
    __shared__ __bf16 lds[2][2][256][BK];   // 128 KiB

    const int tid = threadIdx.x;
    const int lane = tid & 63;
    const int quad = lane >> 4;
    const int l16 = lane & 15;
    const int sa = l16 & 7;            // read-side swizzle key (= frag row & 7)
    const int wave = tid >> 6;         // 8 waves, 2(M) x 4(N)
    const int wm = wave >> 2;
    const int wn = wave & 3;

    const int bm = blockIdx.y * BM;
    const int bn = blockIdx.x * BN;

    // staging per-thread geometry
    const int c8 = tid & 7;            // 16B chunk within a row
    const int r8 = (tid >> 3) & 7;     // dst row & 7 for every stage pattern
    const int scol = (c8 ^ r8) << 3;   // pre-swizzled global source column (elems)
    const int arow = tid >> 3;         // 0..63
    const int bq64 = ((tid >> 8) << 6);// 0 or 64
    const int brow = (tid >> 3) & 31;  // 0..31

    f32x4_t acc[8][4] = {};

#define STAGE_A(buf, mh, k0)                                                        \
  do {                                                                              \
    _Pragma("unroll") for (int r_ = 0; r_ < 2; ++r_) {                              \
      int row_ = r_ * 128 + (mh) * 64 + arow;                                       \
      __builtin_amdgcn_global_load_lds(                                             \
          (const __attribute__((address_space(1))) unsigned int*)(                  \
              A + (size_t)(bm + row_) * K + (k0) + scol),                           \
          (__attribute__((address_space(3))) unsigned int*)(&lds[buf][0][row_][c8 * 8]), \
          16, 0, 0);                                                                \
    }                                                                               \
  } while (0)

#define STAGE_B(buf, nh, k0)                                                        \
  do {                                                                              \
    _Pragma("unroll") for (int r_ = 0; r_ < 2; ++r_) {                              \
      int row_ = r_ * 128 + bq64 + (nh) * 32 + brow;                                \
      __builtin_amdgcn_global_load_lds(                                             \
          (const __attribute__((address_space(1))) unsigned int*)(                  \
              B + (size_t)(bn + row_) * K + (k0) + scol),                           \
          (__attribute__((address_space(3))) unsigned int*)(&lds[buf][1][row_][c8 * 8]), \
          16, 0, 0);                                                                \
    }                                                                               \
  } while (0)

#define LOAD_A(buf, mh)                                                             \
  do {                                                                              \
    _Pragma("unroll") for (int i_ = 0; i_ < 4; ++i_) {                              \
      int row_ = wm * 128 + (mh) * 64 + i_ * 16 + l16;                              \
      _Pragma("unroll") for (int ks_ = 0; ks_ < 2; ++ks_)                           \
        a[i_][ks_] = *(const bf16x8_t*)(&lds[buf][0][row_][((ks_ * 4 + quad) ^ sa) << 3]); \
    }                                                                               \
  } while (0)

#define LOAD_B(buf, nh, bv)                                                         \
  do {                                                                              \
    _Pragma("unroll") for (int j_ = 0; j_ < 2; ++j_) {                              \
      int row_ = wn * 64 + (nh) * 32 + j_ * 16 + l16;                               \
      _Pragma("unroll") for (int ks_ = 0; ks_ < 2; ++ks_)                           \
        bv[j_][ks_] = *(const bf16x8_t*)(&lds[buf][1][row_][((ks_ * 4 + quad) ^ sa) << 3]); \
    }                                                                               \
  } while (0)

#define MFMA_Q(mh, nh, bv)                                                          \
  do {                                                                              \
    __builtin_amdgcn_s_setprio(1);                                                  \
    _Pragma("unroll") for (int i_ = 0; i_ < 4; ++i_)                                \
      _Pragma("unroll") for (int j_ = 0; j_ < 2; ++j_) {                            \
        acc[(mh) * 4 + i_][(nh) * 2 + j_] = __builtin_amdgcn_mfma_f32_16x16x32_bf16( \
            a[i_][0], bv[j_][0], acc[(mh) * 4 + i_][(nh) * 2 + j_], 0, 0, 0);       \
        acc[(mh) * 4 + i_][(nh) * 2 + j_] = __builtin_amdgcn_mfma_f32_16x16x32_bf16( \
            a[i_][1], bv[j_][1], acc[(mh) * 4 + i_][(nh) * 2 + j_], 0, 0, 0);       \
      }                                                                             \
    __builtin_amdgcn_s_setprio(0);                                                  \
  } while (0)

#define FENCE() asm volatile("" ::: "memory")
#define BAR()   do { FENCE(); __builtin_amdgcn_s_barrier(); FENCE(); } while (0)
#define VMCNT(n_) asm volatile("s_waitcnt vmcnt(" #n_ ")" ::: "memory")

    // Prologue: buf0 = K-tile0 (4 units), buf1 = K-tile1 {u1=A0', u4=B1', u3=A1'}.
    // vmcnt(6): first 8 of 14 loads landed = all of buf0.
    STAGE_A(0, 0, 0);      // buf0.u1  A0
    STAGE_B(0, 0, 0);      // buf0.u2  B0
    STAGE_B(0, 1, 0);      // buf0.u4  B1
    STAGE_A(0, 1, 0);      // buf0.u3  A1
    STAGE_A(1, 0, BK);     // buf1.u1  A0'
    STAGE_B(1, 1, BK);     // buf1.u4  B1'
    STAGE_A(1, 1, BK);     // buf1.u3  A1'
    VMCNT(6);
    BAR();

    bf16x8_t a[4][2], b0[2][2], b1[2][2];
    // Pre-loop reads for p1's MFMA q00 (the "p8 reads" of iteration -1).
    LOAD_A(0, 0);          // A0
    LOAD_B(0, 0, b0);      // B0

    for (int it = 0; it < 8; ++it) {
        const int k1 = it * 128 + 64;                           // real thru it=7
        int k2 = it * 128 + 128; if (k2 > K - BK) k2 = K - BK;  // clamp: garbage into
        int k3 = it * 128 + 192; if (k3 > K - BK) k3 = K - BK;  // dead regions, in-bounds

        // p1
        STAGE_B(1, 0, k1);     // buf1.u2  B0' (completes tile O staging)
        MFMA_Q(0, 0, b0);      // q00: A0,B0 (read last phase)
        LOAD_B(0, 1, b1);      // read B1 for p2
        BAR();

        // p2
        STAGE_A(0, 0, k2);     // buf0.u1  A0-next
        MFMA_Q(0, 1, b1);      // q01: A0,B1
        LOAD_A(0, 1);          // read A1 for p3 (WAR vs q01's A0 regs)
        BAR();

        // p3
        STAGE_B(0, 0, k2);     // buf0.u2  B0-next
        MFMA_Q(1, 1, b1);      // q11: A1,B1
        VMCNT(4);              // gate: buf1 (tile O) fully landed
        BAR();

        // p4
        STAGE_B(0, 1, k2);     // buf0.u4  B1-next
        MFMA_Q(1, 0, b0);      // q10: A1,B0
        LOAD_A(1, 0);          // read A0' for p5 (WAR vs q10's A1)
        LOAD_B(1, 0, b0);      // read B0' for p5 (WAR vs q10's B0)
        BAR();

        // p5
        STAGE_A(0, 1, k2);     // buf0.u3  A1-next
        MFMA_Q(0, 0, b0);      // q00': A0',B0'
        LOAD_B(1, 1, b1);      // read B1' for p6
        BAR();

        // p6
        STAGE_A(1, 0, k3);     // buf1.u1  A0'-nextnext
        MFMA_Q(0, 1, b1);      // q01': A0',B1'
        LOAD_A(1, 1);          // read A1' for p7 (WAR)
        BAR();

        // p7
        STAGE_B(1, 1, k3);     // buf1.u4  B1'-nextnext
        MFMA_Q(1, 1, b1);      // q11': A1',B1'
        VMCNT(4);              // gate: buf0-next fully landed
        BAR();

        // p8
        STAGE_A(1, 1, k3);     // buf1.u3  A1'-nextnext
        MFMA_Q(1, 0, b0);      // q10': A1',B0'
        LOAD_A(0, 0);          // read A0-next for next p1 (WAR)
        LOAD_B(0, 0, b0);      // read B0-next (WAR)
        BAR();
    }

    // Epilogue: direct C stores (round-2 style; RMW fetch costs no time at our
    // HBM utilization). C/D layout (verified m89/m91): col=lane&15, row=quad*4+reg.
    const int crow0 = bm + wm * 128 + quad * 4;
    const int ccol0 = bn + wn * 64 + l16;
#pragma unroll
    for (int i_ = 0; i_ < 8; ++i_)
#pragma unroll
      for (int j_ = 0; j_ < 4; ++j_)
#pragma unroll
        for (int r_ = 0; r_ < 4; ++r_)
          C[(size_t)(crow0 + i_ * 16 + r_) * N + (ccol0 + j_ * 16)] = acc[i_][j_][r_];

#undef STAGE_A
#undef STAGE_B
#undef LOAD_A
#undef LOAD_B
#undef MFMA_Q
#undef FENCE
#undef BAR
#undef VMCNT
}

extern "C" void kernel_launch(void* const* d_in, const int* in_sizes, int n_in,
                              void* d_out, int out_size, void* d_ws, size_t ws_size,
                              hipStream_t stream) {
    const float* in_f32 = (const float*)d_in[0];   // [M,K]
    const float* w_f32  = (const float*)d_in[1];   // [N,K]
    float* out = (float*)d_out;                     // [M,N]

    __bf16* A_bf = (__bf16*)d_ws;
    __bf16* W_bf = A_bf + (size_t)M * K;

    cvt_f32_bf16<<<((size_t)(M + N) * K) / (8 * 256), 256, 0, stream>>>(in_f32, w_f32, A_bf, W_bf);

    dim3 grid(N / BN, M / BM);   // (16, 32) = 512 blocks, 1 block/CU (128 KiB LDS)
    gemm_bt<<<grid, 512, 0, stream>>>(A_bf, W_bf, out);
}